// Round 5
// baseline (322.518 us; speedup 1.0000x reference)
//
#include <hip/hip_runtime.h>
#include <hip/hip_bf16.h>

// GraphAttentionEncoder: 2x GATConv (shared edges) + gated mix + residual + LN
// N=50000, DIM=128, H=4, C=32, E=800000 (+N self loops)
//
// R4 changes vs R3:
//  - k_fill split: counting sort writes only packed (dst<<16)|src (4B scatter,
//    was 20B scatter + 64B random gather per edge). New k_weights computes the
//    per-edge exp weights in dst-sorted order: ssd/w sequential, ed[dst]
//    sequential, es[src] random but L2-resident (1.6 MB).
//  - k_agg inner loop unrolled x8 (was x4) for more gathers in flight.

typedef unsigned short u16;
typedef __bf16 bf16x8 __attribute__((ext_vector_type(8)));
typedef float f32x4 __attribute__((ext_vector_type(4)));

#define LRELU_SLOPE 0.2f
#define LN_EPS 1e-5f

__device__ __forceinline__ float bfbits(unsigned int hi_bits) {
    union { unsigned int i; float f; } v; v.i = hi_bits; return v.f;
}
__device__ __forceinline__ float bflo(unsigned int u) { return bfbits(u << 16); }
__device__ __forceinline__ float bfhi(unsigned int u) { return bfbits(u & 0xFFFF0000u); }
__device__ __forceinline__ u16 f2bf(float f) {
    union { float f; unsigned int i; } v; v.f = f;
    unsigned int lsb = (v.i >> 16) & 1u;
    v.i += 0x7FFFu + lsb;                 // round-to-nearest-even
    return (u16)(v.i >> 16);
}

// wb[col][k] = W[k][col] bf16 (col 0-127 -> W1, 128-255 -> W2); deg[i]=1
__global__ void k_prep(const float* __restrict__ W1, const float* __restrict__ W2,
                       u16* __restrict__ wb, int* __restrict__ deg, int n) {
    int i = blockIdx.x * 256 + threadIdx.x;
    if (i < 32768) {
        int col = i >> 7, k = i & 127;
        float v = (col < 128) ? W1[k * 128 + col] : W2[k * 128 + (col - 128)];
        wb[i] = f2bf(v);
    }
    if (i < n) deg[i] = 1;
}

__global__ void k_count(const int* __restrict__ ei, int* __restrict__ deg, int E) {
    int i = blockIdx.x * 256 + threadIdx.x;
    if (i < E) atomicAdd(&deg[ei[E + i]], 1);
}

__global__ void k_bsum(const int* __restrict__ deg, int* __restrict__ bsum, int n) {
    __shared__ int s[256];
    int i = blockIdx.x * 256 + threadIdx.x;
    s[threadIdx.x] = (i < n) ? deg[i] : 0;
    __syncthreads();
    for (int o = 128; o; o >>= 1) {
        if (threadIdx.x < o) s[threadIdx.x] += s[threadIdx.x + o];
        __syncthreads();
    }
    if (threadIdx.x == 0) bsum[blockIdx.x] = s[0];
}

// each block: redundant scan of bsum[0..nb) for its prefix, then local scan
__global__ void k_scan(const int* __restrict__ deg, const int* __restrict__ bsum,
                       int* __restrict__ offs, int* __restrict__ cursor,
                       int nb, int n) {
    __shared__ int s[256];
    __shared__ int bp;
    int t = threadIdx.x;
    int bv = (t < nb) ? bsum[t] : 0;
    s[t] = bv;
    __syncthreads();
    for (int o = 1; o < 256; o <<= 1) {
        int u = (t >= o) ? s[t - o] : 0;
        __syncthreads();
        s[t] += u;
        __syncthreads();
    }
    if (t == (int)blockIdx.x) bp = s[t] - bv;   // exclusive prefix of this block
    __syncthreads();
    int i = blockIdx.x * 256 + t;
    int v = (i < n) ? deg[i] : 0;
    s[t] = v;
    __syncthreads();
    for (int o = 1; o < 256; o <<= 1) {
        int u = (t >= o) ? s[t - o] : 0;
        __syncthreads();
        s[t] += u;
        __syncthreads();
    }
    if (i < n) {
        int e = bp + s[t] - v;
        offs[i] = e;
        cursor[i] = e;
        if (i == n - 1) offs[n] = e + v;
    }
}

// MFMA GEMM, no LDS. Output packed: hbp[row][c] = (h2[c]<<16)|h1[c], c in [0,128)
__global__ __launch_bounds__(256) void k_gemm(const float* __restrict__ x,
                                              const u16* __restrict__ wb,
                                              unsigned int* __restrict__ hbp, int n) {
    int wave = threadIdx.x >> 6, lane = threadIdx.x & 63;
    int quad = lane >> 4, r16 = lane & 15;
    int row = blockIdx.x * 64 + wave * 16 + r16;
    int arow = (row < n) ? row : n - 1;
    const float* xp = x + (size_t)arow * 128 + quad * 8;
    union { u16 u[8]; bf16x8 b; } ar;
    bf16x8 a[4];
#pragma unroll
    for (int ks = 0; ks < 4; ks++) {
        float4 lo = *(const float4*)(xp + ks * 32);
        float4 hi = *(const float4*)(xp + ks * 32 + 4);
        ar.u[0] = f2bf(lo.x); ar.u[1] = f2bf(lo.y); ar.u[2] = f2bf(lo.z); ar.u[3] = f2bf(lo.w);
        ar.u[4] = f2bf(hi.x); ar.u[5] = f2bf(hi.y); ar.u[6] = f2bf(hi.z); ar.u[7] = f2bf(hi.w);
        a[ks] = ar.b;
    }
    f32x4 acc[16];
#pragma unroll
    for (int t = 0; t < 16; t++) acc[t] = (f32x4){0.f, 0.f, 0.f, 0.f};
    const u16* bbase = wb + r16 * 128 + quad * 8;
#pragma unroll
    for (int t = 0; t < 16; t++) {
        const u16* bp = bbase + t * 2048;      // t*16 rows * 128
#pragma unroll
        for (int ks = 0; ks < 4; ks++) {
            bf16x8 b = *(const bf16x8*)(bp + ks * 32);
            acc[t] = __builtin_amdgcn_mfma_f32_16x16x32_bf16(a[ks], b, acc[t], 0, 0, 0);
        }
    }
    int row0 = blockIdx.x * 64 + wave * 16 + quad * 4;
#pragma unroll
    for (int t = 0; t < 8; t++) {
        int c = t * 16 + r16;                  // packed col 0..127
#pragma unroll
        for (int g = 0; g < 4; g++) {
            int gr = row0 + g;
            if (gr < n) {
                unsigned int pv = ((unsigned int)f2bf(acc[t + 8][g]) << 16) | f2bf(acc[t][g]);
                hbp[(size_t)gr * 128 + c] = pv;
            }
        }
    }
}

// thread per (node, head): both layers from packed row.
// es/ed rows: [node][8], slot = layer*4 + head
__global__ void k_logits(const unsigned int* __restrict__ hbp,
                         const float* __restrict__ as1, const float* __restrict__ ad1,
                         const float* __restrict__ as2, const float* __restrict__ ad2,
                         float* __restrict__ es, float* __restrict__ ed, int n) {
    int i = blockIdx.x * 256 + threadIdx.x;
    if (i >= n * 4) return;
    int node = i >> 2, head = i & 3;
    const uint4* hv = (const uint4*)(hbp + (size_t)node * 128 + head * 32);
    const float* a1 = as1 + head * 32;
    const float* d1 = ad1 + head * 32;
    const float* a2 = as2 + head * 32;
    const float* d2 = ad2 + head * 32;
    float s1 = 0.f, t1 = 0.f, s2 = 0.f, t2 = 0.f;
#pragma unroll
    for (int q = 0; q < 8; q++) {
        uint4 w = hv[q];
        unsigned int ws[4] = {w.x, w.y, w.z, w.w};
#pragma unroll
        for (int h = 0; h < 4; h++) {
            int c = q * 4 + h;
            float v1 = bflo(ws[h]), v2 = bfhi(ws[h]);
            s1 += v1 * a1[c]; t1 += v1 * d1[c];
            s2 += v2 * a2[c]; t2 += v2 * d2[c];
        }
    }
    es[node * 8 + head]     = s1;
    ed[node * 8 + head]     = t1;
    es[node * 8 + 4 + head] = s2;
    ed[node * 8 + 4 + head] = t2;
}

// counting sort only: ssd[pos] = (dst<<16) | src  (n <= 65536)
__global__ void k_fill(const int* __restrict__ ei, int* __restrict__ cursor,
                       unsigned int* __restrict__ ssd, int E, int n) {
    int i = blockIdx.x * 256 + threadIdx.x;
    if (i >= E + n) return;
    int s, d;
    if (i < E) { s = ei[i]; d = ei[E + i]; } else { s = i - E; d = s; }
    int pos = atomicAdd(&cursor[d], 1);
    ssd[pos] = ((unsigned int)d << 16) | (unsigned int)s;
}

// dst-sorted weight pass: sequential ssd/w streams, ed[dst] sequential,
// es[src] random but L2-resident (1.6 MB).
// w[pos][h] = (bf16(exp(lrelu(e2)))<<16) | bf16(exp(lrelu(e1))), h in [0,4)
__global__ void k_weights(const unsigned int* __restrict__ ssd,
                          const float* __restrict__ es, const float* __restrict__ ed,
                          uint4* __restrict__ w, int m) {
    int i = blockIdx.x * 256 + threadIdx.x;
    if (i >= m) return;
    unsigned int sd = ssd[i];
    int s = sd & 0xFFFF, d = sd >> 16;
    float4 eslo = *(const float4*)(es + s * 8);
    float4 eshi = *(const float4*)(es + s * 8 + 4);
    float4 edlo = *(const float4*)(ed + d * 8);
    float4 edhi = *(const float4*)(ed + d * 8 + 4);
    float e1[4] = {eslo.x + edlo.x, eslo.y + edlo.y, eslo.z + edlo.z, eslo.w + edlo.w};
    float e2[4] = {eshi.x + edhi.x, eshi.y + edhi.y, eshi.z + edhi.z, eshi.w + edhi.w};
    unsigned int uw[4];
#pragma unroll
    for (int h = 0; h < 4; h++) {
        float a = e1[h]; a = (a > 0.f) ? a : LRELU_SLOPE * a;
        float b = e2[h]; b = (b > 0.f) ? b : LRELU_SLOPE * b;
        uw[h] = ((unsigned int)f2bf(__expf(b)) << 16) | f2bf(__expf(a));
    }
    w[i] = make_uint4(uw[0], uw[1], uw[2], uw[3]);
}

__device__ __forceinline__ float wred(float v) {
#pragma unroll
    for (int off = 32; off; off >>= 1) v += __shfl_xor(v, off, 64);
    return v;
}

__device__ __forceinline__ unsigned int hsel(uint4 w, int head) {
    unsigned int r = (head == 0) ? w.x : (head == 1) ? w.y : (head == 2) ? w.z : w.w;
    return r;
}

// one wave per node; lane owns packed cols ca=2*lane, cb=2*lane+1 (same head).
// Inner loop unrolled x8 for memory-level parallelism.
__global__ __launch_bounds__(256) void k_agg(
    const int* __restrict__ offs, const unsigned int* __restrict__ ssd,
    const unsigned int* __restrict__ hbp, const uint4* __restrict__ w4,
    const float* __restrict__ b1, const float* __restrict__ b2,
    const float* __restrict__ gW, const float* __restrict__ gb,
    const float* __restrict__ x, const float* __restrict__ gamma,
    const float* __restrict__ beta, float* __restrict__ out, int n) {
    int wave = threadIdx.x >> 6, lane = threadIdx.x & 63;
    int node = blockIdx.x * 4 + wave;
    if (node >= n) return;
    node = __builtin_amdgcn_readfirstlane(node);   // wave-uniform -> s_loads

    int ca = lane * 2, cb = ca + 1;
    int head = lane >> 4;                  // = ca>>5

    float l1 = 0.f, l2 = 0.f;
    float a1a = 0.f, a1b = 0.f, a2a = 0.f, a2b = 0.f;

    int beg = offs[node], end = offs[node + 1];
    int k = beg;
#define ACC(wp, q) { \
        float ww1 = bflo(wp), ww2 = bfhi(wp); \
        l1 += ww1; l2 += ww2; \
        a1a += ww1 * bflo(q.x); a1b += ww1 * bflo(q.y); \
        a2a += ww2 * bfhi(q.x); a2b += ww2 * bfhi(q.y); }
    for (; k + 7 < end; k += 8) {
        unsigned int j0 = ssd[k] & 0xFFFF,     j1 = ssd[k + 1] & 0xFFFF;
        unsigned int j2 = ssd[k + 2] & 0xFFFF, j3 = ssd[k + 3] & 0xFFFF;
        unsigned int j4 = ssd[k + 4] & 0xFFFF, j5 = ssd[k + 5] & 0xFFFF;
        unsigned int j6 = ssd[k + 6] & 0xFFFF, j7 = ssd[k + 7] & 0xFFFF;
        uint2 q0 = *(const uint2*)(hbp + (size_t)j0 * 128 + ca);
        uint2 q1 = *(const uint2*)(hbp + (size_t)j1 * 128 + ca);
        uint2 q2 = *(const uint2*)(hbp + (size_t)j2 * 128 + ca);
        uint2 q3 = *(const uint2*)(hbp + (size_t)j3 * 128 + ca);
        uint2 q4 = *(const uint2*)(hbp + (size_t)j4 * 128 + ca);
        uint2 q5 = *(const uint2*)(hbp + (size_t)j5 * 128 + ca);
        uint2 q6 = *(const uint2*)(hbp + (size_t)j6 * 128 + ca);
        uint2 q7 = *(const uint2*)(hbp + (size_t)j7 * 128 + ca);
        uint4 w0 = w4[k],     w1v = w4[k + 1], w2v = w4[k + 2], w3v = w4[k + 3];
        uint4 w4v = w4[k + 4], w5v = w4[k + 5], w6v = w4[k + 6], w7v = w4[k + 7];
        unsigned int wp0 = hsel(w0, head),  wp1 = hsel(w1v, head);
        unsigned int wp2 = hsel(w2v, head), wp3 = hsel(w3v, head);
        unsigned int wp4 = hsel(w4v, head), wp5 = hsel(w5v, head);
        unsigned int wp6 = hsel(w6v, head), wp7 = hsel(w7v, head);
        ACC(wp0, q0) ACC(wp1, q1) ACC(wp2, q2) ACC(wp3, q3)
        ACC(wp4, q4) ACC(wp5, q5) ACC(wp6, q6) ACC(wp7, q7)
    }
    for (; k < end; k++) {
        unsigned int j = ssd[k] & 0xFFFF;
        uint4 wv = w4[k];
        uint2 q = *(const uint2*)(hbp + (size_t)j * 128 + ca);
        unsigned int wp = hsel(wv, head);
        ACC(wp, q)
    }
#undef ACC

    float2 b1v = *(const float2*)(b1 + ca);
    float2 b2v = *(const float2*)(b2 + ca);
    float r1 = 1.f / l1, r2 = 1.f / l2;
    float o1a = a1a * r1 + b1v.x;
    float o1b = a1b * r1 + b1v.y;
    float o2a = a2a * r2 + b2v.x;
    float o2b = a2b * r2 + b2v.y;

    // gate logits: concat(out1,out2) @ gate_W(256x2) + gate_b
    float2 g1a = *(const float2*)(gW + 2 * ca);          // rows ca,cb
    float2 g1b = *(const float2*)(gW + 2 * cb);
    float2 g2a = *(const float2*)(gW + 2 * (128 + ca));
    float2 g2b = *(const float2*)(gW + 2 * (128 + cb));
    float p0 = o1a * g1a.x + o1b * g1b.x + o2a * g2a.x + o2b * g2b.x;
    float p1 = o1a * g1a.y + o1b * g1b.y + o2a * g2a.y + o2b * g2b.y;
    p0 = wred(p0) + gb[0];
    p1 = wred(p1) + gb[1];
    float mg = fmaxf(p0, p1);
    float eg0 = __expf(p0 - mg), eg1 = __expf(p1 - mg);
    float g0 = eg0 / (eg0 + eg1), g1 = 1.f - g0;

    float2 xv = *(const float2*)(x + (size_t)node * 128 + ca);
    float ya = xv.x + g0 * o1a + g1 * o2a;
    float yb = xv.y + g0 * o1b + g1 * o2b;

    float s  = wred(ya + yb);
    float ss = wred(ya * ya + yb * yb);
    float mean = s * (1.f / 128.f);
    float var  = ss * (1.f / 128.f) - mean * mean;
    float rstd = rsqrtf(var + LN_EPS);
    float2 gv = *(const float2*)(gamma + ca);
    float2 bv = *(const float2*)(beta + ca);
    float2 ov;
    ov.x = (ya - mean) * rstd * gv.x + bv.x;
    ov.y = (yb - mean) * rstd * gv.y + bv.y;
    *(float2*)(out + (size_t)node * 128 + ca) = ov;
}

extern "C" void kernel_launch(void* const* d_in, const int* in_sizes, int n_in,
                              void* d_out, int out_size, void* d_ws, size_t ws_size,
                              hipStream_t stream) {
    const float* x   = (const float*)d_in[0];
    const int*   ei  = (const int*)d_in[1];
    const float* W1  = (const float*)d_in[2];
    const float* b1  = (const float*)d_in[3];
    const float* as1 = (const float*)d_in[4];
    const float* ad1 = (const float*)d_in[5];
    const float* W2  = (const float*)d_in[6];
    const float* b2  = (const float*)d_in[7];
    const float* as2 = (const float*)d_in[8];
    const float* ad2 = (const float*)d_in[9];
    const float* gW  = (const float*)d_in[10];
    const float* gb  = (const float*)d_in[11];
    const float* gamma = (const float*)d_in[12];
    const float* beta  = (const float*)d_in[13];
    float* out = (float*)d_out;

    int n = in_sizes[0] / 128;
    int E = in_sizes[1] / 2;
    int m = E + n;

    char* p = (char*)d_ws;
    auto take = [&](size_t bytes) {
        char* q = p;
        p += (bytes + 255) & ~(size_t)255;
        return (void*)q;
    };
    u16* wb    = (u16*)take((size_t)256 * 128 * 2);
    unsigned int* hbp = (unsigned int*)take((size_t)n * 128 * 4);
    float* es  = (float*)take((size_t)n * 8 * 4);
    float* ed  = (float*)take((size_t)n * 8 * 4);
    int* deg    = (int*)take((size_t)n * 4);
    int* offs   = (int*)take((size_t)(n + 1) * 4);
    int* cursor = (int*)take((size_t)n * 4);
    int* bsum   = (int*)take((size_t)256 * 4);
    unsigned int* ssd = (unsigned int*)take((size_t)m * 4);
    uint4* w    = (uint4*)take((size_t)m * 16);

    int nb = (n + 255) / 256;   // 196 (<= 256 required by k_scan)

    k_prep<<<nb, 256, 0, stream>>>(W1, W2, wb, deg, n);
    k_count<<<(E + 255) / 256, 256, 0, stream>>>(ei, deg, E);
    k_bsum<<<nb, 256, 0, stream>>>(deg, bsum, n);
    k_scan<<<nb, 256, 0, stream>>>(deg, bsum, offs, cursor, nb, n);
    k_gemm<<<(n + 63) / 64, 256, 0, stream>>>(x, wb, hbp, n);
    k_logits<<<(n * 4 + 255) / 256, 256, 0, stream>>>(hbp, as1, ad1, as2, ad2, es, ed, n);
    k_fill<<<(m + 255) / 256, 256, 0, stream>>>(ei, cursor, ssd, E, n);
    k_weights<<<(m + 255) / 256, 256, 0, stream>>>(ssd, es, ed, w, m);
    k_agg<<<(n + 3) / 4, 256, 0, stream>>>(offs, ssd, hbp, w,
                                           b1, b2, gW, gb, x, gamma, beta, out, n);
}

// Round 6
// 301.736 us; speedup vs baseline: 1.0689x; 1.0689x over previous
//
#include <hip/hip_runtime.h>
#include <hip/hip_bf16.h>

// GraphAttentionEncoder: 2x GATConv (shared edges) + gated mix + residual + LN
// N=50000, DIM=128, H=4, C=32, E=800000 (+N self loops)
//
// R5 changes vs R4:
//  - k_agg reverted to R3 x4 unroll (x8 gave 0 gain, +16 VGPR, -8% occupancy).
//  - k_fill re-fused (R4 split cost +17us: sort pass is atomic-bound, not
//    payload-bound, so the extra pass was pure overhead).
//  - atomic counters sharded x8 by edge-block (shard=(i>>8)&7): deg8/cursor8
//    cut same-cacheline contention 8x in k_count and k_fill. Scan converts
//    deg8 in-place to per-shard cursors (no extra workspace).

typedef unsigned short u16;
typedef __bf16 bf16x8 __attribute__((ext_vector_type(8)));
typedef float f32x4 __attribute__((ext_vector_type(4)));

#define LRELU_SLOPE 0.2f
#define LN_EPS 1e-5f
#define SH 8                 // atomic shards

__device__ __forceinline__ float bfbits(unsigned int hi_bits) {
    union { unsigned int i; float f; } v; v.i = hi_bits; return v.f;
}
__device__ __forceinline__ float bflo(unsigned int u) { return bfbits(u << 16); }
__device__ __forceinline__ float bfhi(unsigned int u) { return bfbits(u & 0xFFFF0000u); }
__device__ __forceinline__ u16 f2bf(float f) {
    union { float f; unsigned int i; } v; v.f = f;
    unsigned int lsb = (v.i >> 16) & 1u;
    v.i += 0x7FFFu + lsb;                 // round-to-nearest-even
    return (u16)(v.i >> 16);
}

// wb[col][k] = W[k][col] bf16; deg8 init: self-loop counted in the shard that
// k_fill's block for item i=E+node will use: shard = ((E+node)>>8)&7.
__global__ void k_prep(const float* __restrict__ W1, const float* __restrict__ W2,
                       u16* __restrict__ wb, int* __restrict__ deg8, int n, int E) {
    int i = blockIdx.x * 256 + threadIdx.x;
    if (i < 32768) {
        int col = i >> 7, k = i & 127;
        float v = (col < 128) ? W1[k * 128 + col] : W2[k * 128 + (col - 128)];
        wb[i] = f2bf(v);
    }
    if (i < n) {
        int ss = ((E + i) >> 8) & (SH - 1);
#pragma unroll
        for (int x = 0; x < SH; x++) deg8[x * n + i] = (x == ss) ? 1 : 0;
    }
}

__global__ void k_count(const int* __restrict__ ei, int* __restrict__ deg8,
                        int E, int n) {
    int i = blockIdx.x * 256 + threadIdx.x;
    if (i < E) {
        int sh = (i >> 8) & (SH - 1);
        atomicAdd(&deg8[sh * n + ei[E + i]], 1);
    }
}

__global__ void k_bsum(const int* __restrict__ deg8, int* __restrict__ bsum, int n) {
    __shared__ int s[256];
    int i = blockIdx.x * 256 + threadIdx.x;
    int v = 0;
    if (i < n) {
#pragma unroll
        for (int x = 0; x < SH; x++) v += deg8[x * n + i];
    }
    s[threadIdx.x] = v;
    __syncthreads();
    for (int o = 128; o; o >>= 1) {
        if (threadIdx.x < o) s[threadIdx.x] += s[threadIdx.x + o];
        __syncthreads();
    }
    if (threadIdx.x == 0) bsum[blockIdx.x] = s[0];
}

// scan -> offs; deg8 converted IN-PLACE to per-shard cursors:
// cursor[x][i] = offs[i] + sum_{y<x} deg[y][i]
__global__ void k_scan(int* __restrict__ deg8, const int* __restrict__ bsum,
                       int* __restrict__ offs, int nb, int n) {
    __shared__ int s[256];
    __shared__ int bp;
    int t = threadIdx.x;
    int bv = (t < nb) ? bsum[t] : 0;
    s[t] = bv;
    __syncthreads();
    for (int o = 1; o < 256; o <<= 1) {
        int u = (t >= o) ? s[t - o] : 0;
        __syncthreads();
        s[t] += u;
        __syncthreads();
    }
    if (t == (int)blockIdx.x) bp = s[t] - bv;   // exclusive prefix of this block
    __syncthreads();
    int i = blockIdx.x * 256 + t;
    int d[SH];
    int v = 0;
    if (i < n) {
#pragma unroll
        for (int x = 0; x < SH; x++) { d[x] = deg8[x * n + i]; v += d[x]; }
    }
    s[t] = v;
    __syncthreads();
    for (int o = 1; o < 256; o <<= 1) {
        int u = (t >= o) ? s[t - o] : 0;
        __syncthreads();
        s[t] += u;
        __syncthreads();
    }
    if (i < n) {
        int e = bp + s[t] - v;
        offs[i] = e;
        int run = e;
#pragma unroll
        for (int x = 0; x < SH; x++) { deg8[x * n + i] = run; run += d[x]; }
        if (i == n - 1) offs[n] = e + v;
    }
}

// MFMA GEMM, no LDS. Output packed: hbp[row][c] = (h2[c]<<16)|h1[c], c in [0,128)
__global__ __launch_bounds__(256) void k_gemm(const float* __restrict__ x,
                                              const u16* __restrict__ wb,
                                              unsigned int* __restrict__ hbp, int n) {
    int wave = threadIdx.x >> 6, lane = threadIdx.x & 63;
    int quad = lane >> 4, r16 = lane & 15;
    int row = blockIdx.x * 64 + wave * 16 + r16;
    int arow = (row < n) ? row : n - 1;
    const float* xp = x + (size_t)arow * 128 + quad * 8;
    union { u16 u[8]; bf16x8 b; } ar;
    bf16x8 a[4];
#pragma unroll
    for (int ks = 0; ks < 4; ks++) {
        float4 lo = *(const float4*)(xp + ks * 32);
        float4 hi = *(const float4*)(xp + ks * 32 + 4);
        ar.u[0] = f2bf(lo.x); ar.u[1] = f2bf(lo.y); ar.u[2] = f2bf(lo.z); ar.u[3] = f2bf(lo.w);
        ar.u[4] = f2bf(hi.x); ar.u[5] = f2bf(hi.y); ar.u[6] = f2bf(hi.z); ar.u[7] = f2bf(hi.w);
        a[ks] = ar.b;
    }
    f32x4 acc[16];
#pragma unroll
    for (int t = 0; t < 16; t++) acc[t] = (f32x4){0.f, 0.f, 0.f, 0.f};
    const u16* bbase = wb + r16 * 128 + quad * 8;
#pragma unroll
    for (int t = 0; t < 16; t++) {
        const u16* bp = bbase + t * 2048;      // t*16 rows * 128
#pragma unroll
        for (int ks = 0; ks < 4; ks++) {
            bf16x8 b = *(const bf16x8*)(bp + ks * 32);
            acc[t] = __builtin_amdgcn_mfma_f32_16x16x32_bf16(a[ks], b, acc[t], 0, 0, 0);
        }
    }
    int row0 = blockIdx.x * 64 + wave * 16 + quad * 4;
#pragma unroll
    for (int t = 0; t < 8; t++) {
        int c = t * 16 + r16;                  // packed col 0..127
#pragma unroll
        for (int g = 0; g < 4; g++) {
            int gr = row0 + g;
            if (gr < n) {
                unsigned int pv = ((unsigned int)f2bf(acc[t + 8][g]) << 16) | f2bf(acc[t][g]);
                hbp[(size_t)gr * 128 + c] = pv;
            }
        }
    }
}

// thread per (node, head): both layers from packed row.
// es/ed rows: [node][8], slot = layer*4 + head
__global__ void k_logits(const unsigned int* __restrict__ hbp,
                         const float* __restrict__ as1, const float* __restrict__ ad1,
                         const float* __restrict__ as2, const float* __restrict__ ad2,
                         float* __restrict__ es, float* __restrict__ ed, int n) {
    int i = blockIdx.x * 256 + threadIdx.x;
    if (i >= n * 4) return;
    int node = i >> 2, head = i & 3;
    const uint4* hv = (const uint4*)(hbp + (size_t)node * 128 + head * 32);
    const float* a1 = as1 + head * 32;
    const float* d1 = ad1 + head * 32;
    const float* a2 = as2 + head * 32;
    const float* d2 = ad2 + head * 32;
    float s1 = 0.f, t1 = 0.f, s2 = 0.f, t2 = 0.f;
#pragma unroll
    for (int q = 0; q < 8; q++) {
        uint4 w = hv[q];
        unsigned int ws[4] = {w.x, w.y, w.z, w.w};
#pragma unroll
        for (int h = 0; h < 4; h++) {
            int c = q * 4 + h;
            float v1 = bflo(ws[h]), v2 = bfhi(ws[h]);
            s1 += v1 * a1[c]; t1 += v1 * d1[c];
            s2 += v2 * a2[c]; t2 += v2 * d2[c];
        }
    }
    es[node * 8 + head]     = s1;
    ed[node * 8 + head]     = t1;
    es[node * 8 + 4 + head] = s2;
    ed[node * 8 + 4 + head] = t2;
}

// counting sort (sharded cursors) + per-edge weight computation fused.
// w[pos][h] = (bf16(exp(lrelu(e2)))<<16) | bf16(exp(lrelu(e1))), h in [0,4)
__global__ void k_fill(const int* __restrict__ ei, int* __restrict__ cursor8,
                       const float* __restrict__ es, const float* __restrict__ ed,
                       int* __restrict__ ssrc, uint4* __restrict__ w, int E, int n) {
    int i = blockIdx.x * 256 + threadIdx.x;
    if (i >= E + n) return;
    int s, d;
    if (i < E) { s = ei[i]; d = ei[E + i]; } else { s = i - E; d = s; }
    int sh = (i >> 8) & (SH - 1);
    int pos = atomicAdd(&cursor8[sh * n + d], 1);
    ssrc[pos] = s;
    float4 eslo = *(const float4*)(es + s * 8);
    float4 eshi = *(const float4*)(es + s * 8 + 4);
    float4 edlo = *(const float4*)(ed + d * 8);
    float4 edhi = *(const float4*)(ed + d * 8 + 4);
    float e1[4] = {eslo.x + edlo.x, eslo.y + edlo.y, eslo.z + edlo.z, eslo.w + edlo.w};
    float e2[4] = {eshi.x + edhi.x, eshi.y + edhi.y, eshi.z + edhi.z, eshi.w + edhi.w};
    unsigned int uw[4];
#pragma unroll
    for (int h = 0; h < 4; h++) {
        float a = e1[h]; a = (a > 0.f) ? a : LRELU_SLOPE * a;
        float b = e2[h]; b = (b > 0.f) ? b : LRELU_SLOPE * b;
        uw[h] = ((unsigned int)f2bf(__expf(b)) << 16) | f2bf(__expf(a));
    }
    w[i < E ? pos : pos] = make_uint4(uw[0], uw[1], uw[2], uw[3]);
}

__device__ __forceinline__ float wred(float v) {
#pragma unroll
    for (int off = 32; off; off >>= 1) v += __shfl_xor(v, off, 64);
    return v;
}

__device__ __forceinline__ unsigned int hsel(uint4 w, int head) {
    unsigned int r = (head == 0) ? w.x : (head == 1) ? w.y : (head == 2) ? w.z : w.w;
    return r;
}

// one wave per node; lane owns packed cols ca=2*lane, cb=2*lane+1 (same head).
// Inner loop unrolled x4 for memory-level parallelism (R3-proven).
__global__ __launch_bounds__(256) void k_agg(
    const int* __restrict__ offs, const int* __restrict__ ssrc,
    const unsigned int* __restrict__ hbp, const uint4* __restrict__ w4,
    const float* __restrict__ b1, const float* __restrict__ b2,
    const float* __restrict__ gW, const float* __restrict__ gb,
    const float* __restrict__ x, const float* __restrict__ gamma,
    const float* __restrict__ beta, float* __restrict__ out, int n) {
    int wave = threadIdx.x >> 6, lane = threadIdx.x & 63;
    int node = blockIdx.x * 4 + wave;
    if (node >= n) return;
    node = __builtin_amdgcn_readfirstlane(node);   // wave-uniform -> s_loads

    int ca = lane * 2, cb = ca + 1;
    int head = lane >> 4;                  // = ca>>5

    float l1 = 0.f, l2 = 0.f;
    float a1a = 0.f, a1b = 0.f, a2a = 0.f, a2b = 0.f;

    int beg = offs[node], end = offs[node + 1];
    int k = beg;
#define ACC(wp, q) { \
        float ww1 = bflo(wp), ww2 = bfhi(wp); \
        l1 += ww1; l2 += ww2; \
        a1a += ww1 * bflo(q.x); a1b += ww1 * bflo(q.y); \
        a2a += ww2 * bfhi(q.x); a2b += ww2 * bfhi(q.y); }
    for (; k + 3 < end; k += 4) {
        int j0 = ssrc[k], j1 = ssrc[k + 1], j2 = ssrc[k + 2], j3 = ssrc[k + 3];
        uint4 w0 = w4[k], w1v = w4[k + 1], w2v = w4[k + 2], w3v = w4[k + 3];
        uint2 q0 = *(const uint2*)(hbp + (size_t)j0 * 128 + ca);
        uint2 q1 = *(const uint2*)(hbp + (size_t)j1 * 128 + ca);
        uint2 q2 = *(const uint2*)(hbp + (size_t)j2 * 128 + ca);
        uint2 q3 = *(const uint2*)(hbp + (size_t)j3 * 128 + ca);
        unsigned int wp0 = hsel(w0, head), wp1 = hsel(w1v, head);
        unsigned int wp2 = hsel(w2v, head), wp3 = hsel(w3v, head);
        ACC(wp0, q0) ACC(wp1, q1) ACC(wp2, q2) ACC(wp3, q3)
    }
    for (; k < end; k++) {
        int j = ssrc[k];
        uint4 wv = w4[k];
        uint2 q = *(const uint2*)(hbp + (size_t)j * 128 + ca);
        unsigned int wp = hsel(wv, head);
        ACC(wp, q)
    }
#undef ACC

    float2 b1v = *(const float2*)(b1 + ca);
    float2 b2v = *(const float2*)(b2 + ca);
    float r1 = 1.f / l1, r2 = 1.f / l2;
    float o1a = a1a * r1 + b1v.x;
    float o1b = a1b * r1 + b1v.y;
    float o2a = a2a * r2 + b2v.x;
    float o2b = a2b * r2 + b2v.y;

    // gate logits: concat(out1,out2) @ gate_W(256x2) + gate_b
    float2 g1a = *(const float2*)(gW + 2 * ca);          // rows ca,cb
    float2 g1b = *(const float2*)(gW + 2 * cb);
    float2 g2a = *(const float2*)(gW + 2 * (128 + ca));
    float2 g2b = *(const float2*)(gW + 2 * (128 + cb));
    float p0 = o1a * g1a.x + o1b * g1b.x + o2a * g2a.x + o2b * g2b.x;
    float p1 = o1a * g1a.y + o1b * g1b.y + o2a * g2a.y + o2b * g2b.y;
    p0 = wred(p0) + gb[0];
    p1 = wred(p1) + gb[1];
    float mg = fmaxf(p0, p1);
    float eg0 = __expf(p0 - mg), eg1 = __expf(p1 - mg);
    float g0 = eg0 / (eg0 + eg1), g1 = 1.f - g0;

    float2 xv = *(const float2*)(x + (size_t)node * 128 + ca);
    float ya = xv.x + g0 * o1a + g1 * o2a;
    float yb = xv.y + g0 * o1b + g1 * o2b;

    float s  = wred(ya + yb);
    float ss = wred(ya * ya + yb * yb);
    float mean = s * (1.f / 128.f);
    float var  = ss * (1.f / 128.f) - mean * mean;
    float rstd = rsqrtf(var + LN_EPS);
    float2 gv = *(const float2*)(gamma + ca);
    float2 bv = *(const float2*)(beta + ca);
    float2 ov;
    ov.x = (ya - mean) * rstd * gv.x + bv.x;
    ov.y = (yb - mean) * rstd * gv.y + bv.y;
    *(float2*)(out + (size_t)node * 128 + ca) = ov;
}

extern "C" void kernel_launch(void* const* d_in, const int* in_sizes, int n_in,
                              void* d_out, int out_size, void* d_ws, size_t ws_size,
                              hipStream_t stream) {
    const float* x   = (const float*)d_in[0];
    const int*   ei  = (const int*)d_in[1];
    const float* W1  = (const float*)d_in[2];
    const float* b1  = (const float*)d_in[3];
    const float* as1 = (const float*)d_in[4];
    const float* ad1 = (const float*)d_in[5];
    const float* W2  = (const float*)d_in[6];
    const float* b2  = (const float*)d_in[7];
    const float* as2 = (const float*)d_in[8];
    const float* ad2 = (const float*)d_in[9];
    const float* gW  = (const float*)d_in[10];
    const float* gb  = (const float*)d_in[11];
    const float* gamma = (const float*)d_in[12];
    const float* beta  = (const float*)d_in[13];
    float* out = (float*)d_out;

    int n = in_sizes[0] / 128;
    int E = in_sizes[1] / 2;
    int m = E + n;

    char* p = (char*)d_ws;
    auto take = [&](size_t bytes) {
        char* q = p;
        p += (bytes + 255) & ~(size_t)255;
        return (void*)q;
    };
    u16* wb    = (u16*)take((size_t)256 * 128 * 2);
    unsigned int* hbp = (unsigned int*)take((size_t)n * 128 * 4);
    float* es  = (float*)take((size_t)n * 8 * 4);
    float* ed  = (float*)take((size_t)n * 8 * 4);
    int* deg8  = (int*)take((size_t)SH * n * 4);   // becomes cursor8 after k_scan
    int* offs  = (int*)take((size_t)(n + 1) * 4);
    int* bsum  = (int*)take((size_t)256 * 4);
    int* ssrc  = (int*)take((size_t)m * 4);
    uint4* w   = (uint4*)take((size_t)m * 16);

    int nb = (n + 255) / 256;   // 196 (<= 256 required by k_scan)

    k_prep<<<nb, 256, 0, stream>>>(W1, W2, wb, deg8, n, E);
    k_count<<<(E + 255) / 256, 256, 0, stream>>>(ei, deg8, E, n);
    k_bsum<<<nb, 256, 0, stream>>>(deg8, bsum, n);
    k_scan<<<nb, 256, 0, stream>>>(deg8, bsum, offs, nb, n);
    k_gemm<<<(n + 63) / 64, 256, 0, stream>>>(x, wb, hbp, n);
    k_logits<<<(n * 4 + 255) / 256, 256, 0, stream>>>(hbp, as1, ad1, as2, ad2, es, ed, n);
    k_fill<<<(m + 255) / 256, 256, 0, stream>>>(ei, deg8, es, ed, ssrc, w, E, n);
    k_agg<<<(n + 3) / 4, 256, 0, stream>>>(offs, ssrc, hbp, w,
                                           b1, b2, gW, gb, x, gamma, beta, out, n);
}

// Round 7
// 273.108 us; speedup vs baseline: 1.1809x; 1.1048x over previous
//
#include <hip/hip_runtime.h>
#include <hip/hip_bf16.h>

// GraphAttentionEncoder: 2x GATConv (shared edges) + gated mix + residual + LN
// N=50000, DIM=128, H=4, C=32, E=800000 (+N self loops)
//
// R6 changes vs R5:
//  - self-loops removed from CSR: k_agg adds the self term analytically
//    (fp32 weight from es/ed[node], coalesced hbp[node] row read). k_fill
//    handles exactly E edges; prep inits deg8 to zero.
//  - block-range fusion of independent phases: K2 = gemm || count,
//    K3 = logits || bsum. 8 -> 6 dispatches, chains overlap.
//  - k_agg inner loop unchanged (R3-proven x4 unroll, 20 VGPR).

typedef unsigned short u16;
typedef __bf16 bf16x8 __attribute__((ext_vector_type(8)));
typedef float f32x4 __attribute__((ext_vector_type(4)));

#define LRELU_SLOPE 0.2f
#define LN_EPS 1e-5f
#define SH 8                 // atomic shards

__device__ __forceinline__ float bfbits(unsigned int hi_bits) {
    union { unsigned int i; float f; } v; v.i = hi_bits; return v.f;
}
__device__ __forceinline__ float bflo(unsigned int u) { return bfbits(u << 16); }
__device__ __forceinline__ float bfhi(unsigned int u) { return bfbits(u & 0xFFFF0000u); }
__device__ __forceinline__ u16 f2bf(float f) {
    union { float f; unsigned int i; } v; v.f = f;
    unsigned int lsb = (v.i >> 16) & 1u;
    v.i += 0x7FFFu + lsb;                 // round-to-nearest-even
    return (u16)(v.i >> 16);
}

// wb[col][k] = W[k][col] bf16 (col 0-127 -> W1, 128-255 -> W2); deg8 = 0
__global__ void k_prep(const float* __restrict__ W1, const float* __restrict__ W2,
                       u16* __restrict__ wb, int* __restrict__ deg8, int n) {
    int i = blockIdx.x * 256 + threadIdx.x;
    if (i < 32768) {
        int col = i >> 7, k = i & 127;
        float v = (col < 128) ? W1[k * 128 + col] : W2[k * 128 + (col - 128)];
        wb[i] = f2bf(v);
    }
    if (i < n) {
#pragma unroll
        for (int x = 0; x < SH; x++) deg8[x * n + i] = 0;
    }
}

// K2: blocks [0,Gg) = MFMA GEMM, blocks [Gg,Gg+Gc) = degree count.
// GEMM output packed: hbp[row][c] = (h2[c]<<16)|h1[c], c in [0,128)
__global__ __launch_bounds__(256) void k_cg(const float* __restrict__ x,
                                            const u16* __restrict__ wb,
                                            unsigned int* __restrict__ hbp, int n,
                                            const int* __restrict__ ei,
                                            int* __restrict__ deg8, int E, int Gg) {
    if ((int)blockIdx.x >= Gg) {
        int i = ((int)blockIdx.x - Gg) * 256 + threadIdx.x;
        if (i < E) {
            int sh = (i >> 8) & (SH - 1);
            atomicAdd(&deg8[sh * n + ei[E + i]], 1);
        }
        return;
    }
    int wave = threadIdx.x >> 6, lane = threadIdx.x & 63;
    int quad = lane >> 4, r16 = lane & 15;
    int row = blockIdx.x * 64 + wave * 16 + r16;
    int arow = (row < n) ? row : n - 1;
    const float* xp = x + (size_t)arow * 128 + quad * 8;
    union { u16 u[8]; bf16x8 b; } ar;
    bf16x8 a[4];
#pragma unroll
    for (int ks = 0; ks < 4; ks++) {
        float4 lo = *(const float4*)(xp + ks * 32);
        float4 hi = *(const float4*)(xp + ks * 32 + 4);
        ar.u[0] = f2bf(lo.x); ar.u[1] = f2bf(lo.y); ar.u[2] = f2bf(lo.z); ar.u[3] = f2bf(lo.w);
        ar.u[4] = f2bf(hi.x); ar.u[5] = f2bf(hi.y); ar.u[6] = f2bf(hi.z); ar.u[7] = f2bf(hi.w);
        a[ks] = ar.b;
    }
    f32x4 acc[16];
#pragma unroll
    for (int t = 0; t < 16; t++) acc[t] = (f32x4){0.f, 0.f, 0.f, 0.f};
    const u16* bbase = wb + r16 * 128 + quad * 8;
#pragma unroll
    for (int t = 0; t < 16; t++) {
        const u16* bp = bbase + t * 2048;      // t*16 rows * 128
#pragma unroll
        for (int ks = 0; ks < 4; ks++) {
            bf16x8 b = *(const bf16x8*)(bp + ks * 32);
            acc[t] = __builtin_amdgcn_mfma_f32_16x16x32_bf16(a[ks], b, acc[t], 0, 0, 0);
        }
    }
    int row0 = blockIdx.x * 64 + wave * 16 + quad * 4;
#pragma unroll
    for (int t = 0; t < 8; t++) {
        int c = t * 16 + r16;                  // packed col 0..127
#pragma unroll
        for (int g = 0; g < 4; g++) {
            int gr = row0 + g;
            if (gr < n) {
                unsigned int pv = ((unsigned int)f2bf(acc[t + 8][g]) << 16) | f2bf(acc[t][g]);
                hbp[(size_t)gr * 128 + c] = pv;
            }
        }
    }
}

// K3: blocks [0,Gl) = per-(node,head) logits, blocks [Gl,Gl+nb) = block sums.
// es/ed rows: [node][8], slot = layer*4 + head
__global__ void k_lb(const unsigned int* __restrict__ hbp,
                     const float* __restrict__ as1, const float* __restrict__ ad1,
                     const float* __restrict__ as2, const float* __restrict__ ad2,
                     float* __restrict__ es, float* __restrict__ ed, int n,
                     const int* __restrict__ deg8, int* __restrict__ bsum, int Gl) {
    __shared__ int s[256];
    if ((int)blockIdx.x >= Gl) {
        int bid = (int)blockIdx.x - Gl;
        int i = bid * 256 + threadIdx.x;
        int v = 0;
        if (i < n) {
#pragma unroll
            for (int x = 0; x < SH; x++) v += deg8[x * n + i];
        }
        s[threadIdx.x] = v;
        __syncthreads();
        for (int o = 128; o; o >>= 1) {
            if (threadIdx.x < o) s[threadIdx.x] += s[threadIdx.x + o];
            __syncthreads();
        }
        if (threadIdx.x == 0) bsum[bid] = s[0];
        return;
    }
    int i = blockIdx.x * 256 + threadIdx.x;
    if (i >= n * 4) return;
    int node = i >> 2, head = i & 3;
    const uint4* hv = (const uint4*)(hbp + (size_t)node * 128 + head * 32);
    const float* a1 = as1 + head * 32;
    const float* d1 = ad1 + head * 32;
    const float* a2 = as2 + head * 32;
    const float* d2 = ad2 + head * 32;
    float s1 = 0.f, t1 = 0.f, s2 = 0.f, t2 = 0.f;
#pragma unroll
    for (int q = 0; q < 8; q++) {
        uint4 w = hv[q];
        unsigned int ws[4] = {w.x, w.y, w.z, w.w};
#pragma unroll
        for (int h = 0; h < 4; h++) {
            int c = q * 4 + h;
            float v1 = bflo(ws[h]), v2 = bfhi(ws[h]);
            s1 += v1 * a1[c]; t1 += v1 * d1[c];
            s2 += v2 * a2[c]; t2 += v2 * d2[c];
        }
    }
    es[node * 8 + head]     = s1;
    ed[node * 8 + head]     = t1;
    es[node * 8 + 4 + head] = s2;
    ed[node * 8 + 4 + head] = t2;
}

// scan -> offs; deg8 converted IN-PLACE to per-shard cursors:
// cursor[x][i] = offs[i] + sum_{y<x} deg[y][i]
__global__ void k_scan(int* __restrict__ deg8, const int* __restrict__ bsum,
                       int* __restrict__ offs, int nb, int n) {
    __shared__ int s[256];
    __shared__ int bp;
    int t = threadIdx.x;
    int bv = (t < nb) ? bsum[t] : 0;
    s[t] = bv;
    __syncthreads();
    for (int o = 1; o < 256; o <<= 1) {
        int u = (t >= o) ? s[t - o] : 0;
        __syncthreads();
        s[t] += u;
        __syncthreads();
    }
    if (t == (int)blockIdx.x) bp = s[t] - bv;   // exclusive prefix of this block
    __syncthreads();
    int i = blockIdx.x * 256 + t;
    int d[SH];
    int v = 0;
    if (i < n) {
#pragma unroll
        for (int x = 0; x < SH; x++) { d[x] = deg8[x * n + i]; v += d[x]; }
    }
    s[t] = v;
    __syncthreads();
    for (int o = 1; o < 256; o <<= 1) {
        int u = (t >= o) ? s[t - o] : 0;
        __syncthreads();
        s[t] += u;
        __syncthreads();
    }
    if (i < n) {
        int e = bp + s[t] - v;
        offs[i] = e;
        int run = e;
#pragma unroll
        for (int x = 0; x < SH; x++) { deg8[x * n + i] = run; run += d[x]; }
        if (i == n - 1) offs[n] = e + v;
    }
}

// counting sort (sharded cursors) + per-edge weight computation fused.
// w[pos][h] = (bf16(exp(lrelu(e2)))<<16) | bf16(exp(lrelu(e1))), h in [0,4)
__global__ void k_fill(const int* __restrict__ ei, int* __restrict__ cursor8,
                       const float* __restrict__ es, const float* __restrict__ ed,
                       int* __restrict__ ssrc, uint4* __restrict__ w, int E, int n) {
    int i = blockIdx.x * 256 + threadIdx.x;
    if (i >= E) return;
    int s = ei[i], d = ei[E + i];
    int sh = (i >> 8) & (SH - 1);
    int pos = atomicAdd(&cursor8[sh * n + d], 1);
    ssrc[pos] = s;
    float4 eslo = *(const float4*)(es + s * 8);
    float4 eshi = *(const float4*)(es + s * 8 + 4);
    float4 edlo = *(const float4*)(ed + d * 8);
    float4 edhi = *(const float4*)(ed + d * 8 + 4);
    float e1[4] = {eslo.x + edlo.x, eslo.y + edlo.y, eslo.z + edlo.z, eslo.w + edlo.w};
    float e2[4] = {eshi.x + edhi.x, eshi.y + edhi.y, eshi.z + edhi.z, eshi.w + edhi.w};
    unsigned int uw[4];
#pragma unroll
    for (int h = 0; h < 4; h++) {
        float a = e1[h]; a = (a > 0.f) ? a : LRELU_SLOPE * a;
        float b = e2[h]; b = (b > 0.f) ? b : LRELU_SLOPE * b;
        uw[h] = ((unsigned int)f2bf(__expf(b)) << 16) | f2bf(__expf(a));
    }
    w[pos] = make_uint4(uw[0], uw[1], uw[2], uw[3]);
}

__device__ __forceinline__ float wred(float v) {
#pragma unroll
    for (int off = 32; off; off >>= 1) v += __shfl_xor(v, off, 64);
    return v;
}

__device__ __forceinline__ unsigned int hsel(uint4 w, int head) {
    unsigned int r = (head == 0) ? w.x : (head == 1) ? w.y : (head == 2) ? w.z : w.w;
    return r;
}

// one wave per node; lane owns packed cols ca=2*lane, cb=2*lane+1 (same head).
// Self-loop handled analytically (fp32 weight, coalesced hbp[node] read).
__global__ __launch_bounds__(256) void k_agg(
    const int* __restrict__ offs, const int* __restrict__ ssrc,
    const unsigned int* __restrict__ hbp, const uint4* __restrict__ w4,
    const float* __restrict__ es, const float* __restrict__ ed,
    const float* __restrict__ b1, const float* __restrict__ b2,
    const float* __restrict__ gW, const float* __restrict__ gb,
    const float* __restrict__ x, const float* __restrict__ gamma,
    const float* __restrict__ beta, float* __restrict__ out, int n) {
    int wave = threadIdx.x >> 6, lane = threadIdx.x & 63;
    int node = blockIdx.x * 4 + wave;
    if (node >= n) return;
    node = __builtin_amdgcn_readfirstlane(node);   // wave-uniform -> s_loads

    int ca = lane * 2, cb = ca + 1;
    int head = lane >> 4;                  // = ca>>5

    // self-loop term
    const float* esp = es + node * 8;
    const float* edp = ed + node * 8;
    float e1s = esp[head] + edp[head];
    float e2s = esp[4 + head] + edp[4 + head];
    e1s = (e1s > 0.f) ? e1s : LRELU_SLOPE * e1s;
    e2s = (e2s > 0.f) ? e2s : LRELU_SLOPE * e2s;
    float w1s = __expf(e1s), w2s = __expf(e2s);
    uint2 qs = *(const uint2*)(hbp + (size_t)node * 128 + ca);
    float l1 = w1s, l2 = w2s;
    float a1a = w1s * bflo(qs.x), a1b = w1s * bflo(qs.y);
    float a2a = w2s * bfhi(qs.x), a2b = w2s * bfhi(qs.y);

    int beg = offs[node], end = offs[node + 1];
    int k = beg;
#define ACC(wp, q) { \
        float ww1 = bflo(wp), ww2 = bfhi(wp); \
        l1 += ww1; l2 += ww2; \
        a1a += ww1 * bflo(q.x); a1b += ww1 * bflo(q.y); \
        a2a += ww2 * bfhi(q.x); a2b += ww2 * bfhi(q.y); }
    for (; k + 3 < end; k += 4) {
        int j0 = ssrc[k], j1 = ssrc[k + 1], j2 = ssrc[k + 2], j3 = ssrc[k + 3];
        uint4 w0 = w4[k], w1v = w4[k + 1], w2v = w4[k + 2], w3v = w4[k + 3];
        uint2 q0 = *(const uint2*)(hbp + (size_t)j0 * 128 + ca);
        uint2 q1 = *(const uint2*)(hbp + (size_t)j1 * 128 + ca);
        uint2 q2 = *(const uint2*)(hbp + (size_t)j2 * 128 + ca);
        uint2 q3 = *(const uint2*)(hbp + (size_t)j3 * 128 + ca);
        unsigned int wp0 = hsel(w0, head), wp1 = hsel(w1v, head);
        unsigned int wp2 = hsel(w2v, head), wp3 = hsel(w3v, head);
        ACC(wp0, q0) ACC(wp1, q1) ACC(wp2, q2) ACC(wp3, q3)
    }
    for (; k < end; k++) {
        int j = ssrc[k];
        uint4 wv = w4[k];
        uint2 q = *(const uint2*)(hbp + (size_t)j * 128 + ca);
        unsigned int wp = hsel(wv, head);
        ACC(wp, q)
    }
#undef ACC

    float2 b1v = *(const float2*)(b1 + ca);
    float2 b2v = *(const float2*)(b2 + ca);
    float r1 = 1.f / l1, r2 = 1.f / l2;
    float o1a = a1a * r1 + b1v.x;
    float o1b = a1b * r1 + b1v.y;
    float o2a = a2a * r2 + b2v.x;
    float o2b = a2b * r2 + b2v.y;

    // gate logits: concat(out1,out2) @ gate_W(256x2) + gate_b
    float2 g1a = *(const float2*)(gW + 2 * ca);          // rows ca,cb
    float2 g1b = *(const float2*)(gW + 2 * cb);
    float2 g2a = *(const float2*)(gW + 2 * (128 + ca));
    float2 g2b = *(const float2*)(gW + 2 * (128 + cb));
    float p0 = o1a * g1a.x + o1b * g1b.x + o2a * g2a.x + o2b * g2b.x;
    float p1 = o1a * g1a.y + o1b * g1b.y + o2a * g2a.y + o2b * g2b.y;
    p0 = wred(p0) + gb[0];
    p1 = wred(p1) + gb[1];
    float mg = fmaxf(p0, p1);
    float eg0 = __expf(p0 - mg), eg1 = __expf(p1 - mg);
    float g0 = eg0 / (eg0 + eg1), g1 = 1.f - g0;

    float2 xv = *(const float2*)(x + (size_t)node * 128 + ca);
    float ya = xv.x + g0 * o1a + g1 * o2a;
    float yb = xv.y + g0 * o1b + g1 * o2b;

    float s  = wred(ya + yb);
    float ss = wred(ya * ya + yb * yb);
    float mean = s * (1.f / 128.f);
    float var  = ss * (1.f / 128.f) - mean * mean;
    float rstd = rsqrtf(var + LN_EPS);
    float2 gv = *(const float2*)(gamma + ca);
    float2 bv = *(const float2*)(beta + ca);
    float2 ov;
    ov.x = (ya - mean) * rstd * gv.x + bv.x;
    ov.y = (yb - mean) * rstd * gv.y + bv.y;
    *(float2*)(out + (size_t)node * 128 + ca) = ov;
}

extern "C" void kernel_launch(void* const* d_in, const int* in_sizes, int n_in,
                              void* d_out, int out_size, void* d_ws, size_t ws_size,
                              hipStream_t stream) {
    const float* x   = (const float*)d_in[0];
    const int*   ei  = (const int*)d_in[1];
    const float* W1  = (const float*)d_in[2];
    const float* b1  = (const float*)d_in[3];
    const float* as1 = (const float*)d_in[4];
    const float* ad1 = (const float*)d_in[5];
    const float* W2  = (const float*)d_in[6];
    const float* b2  = (const float*)d_in[7];
    const float* as2 = (const float*)d_in[8];
    const float* ad2 = (const float*)d_in[9];
    const float* gW  = (const float*)d_in[10];
    const float* gb  = (const float*)d_in[11];
    const float* gamma = (const float*)d_in[12];
    const float* beta  = (const float*)d_in[13];
    float* out = (float*)d_out;

    int n = in_sizes[0] / 128;
    int E = in_sizes[1] / 2;

    char* p = (char*)d_ws;
    auto take = [&](size_t bytes) {
        char* q = p;
        p += (bytes + 255) & ~(size_t)255;
        return (void*)q;
    };
    u16* wb    = (u16*)take((size_t)256 * 128 * 2);
    unsigned int* hbp = (unsigned int*)take((size_t)n * 128 * 4);
    float* es  = (float*)take((size_t)n * 8 * 4);
    float* ed  = (float*)take((size_t)n * 8 * 4);
    int* deg8  = (int*)take((size_t)SH * n * 4);   // becomes cursor8 after k_scan
    int* offs  = (int*)take((size_t)(n + 1) * 4);
    int* bsum  = (int*)take((size_t)256 * 4);
    int* ssrc  = (int*)take((size_t)E * 4);
    uint4* w   = (uint4*)take((size_t)E * 16);

    int nb = (n + 255) / 256;       // 196 (<= 256 required by k_scan)
    int Gg = (n + 63) / 64;         // gemm blocks
    int Gc = (E + 255) / 256;       // count blocks
    int Gl = (n * 4 + 255) / 256;   // logits blocks

    k_prep<<<nb, 256, 0, stream>>>(W1, W2, wb, deg8, n);
    k_cg<<<Gg + Gc, 256, 0, stream>>>(x, wb, hbp, n, ei, deg8, E, Gg);
    k_lb<<<Gl + nb, 256, 0, stream>>>(hbp, as1, ad1, as2, ad2, es, ed, n,
                                      deg8, bsum, Gl);
    k_scan<<<nb, 256, 0, stream>>>(deg8, bsum, offs, nb, n);
    k_fill<<<Gc, 256, 0, stream>>>(ei, deg8, es, ed, ssrc, w, E, n);
    k_agg<<<(n + 3) / 4, 256, 0, stream>>>(offs, ssrc, hbp, w, es, ed,
                                           b1, b2, gW, gb, x, gamma, beta, out, n);
}